// Round 14
// baseline (259.983 us; speedup 1.0000x reference)
//
#include <hip/hip_runtime.h>
#include <hip/hip_bf16.h>

constexpr int Bb = 2, Hh = 32, Ss = 1024, Dd = 64;
constexpr int NBH = Bb * Hh;     // 64

// ---- bf16 pair packing (round-to-nearest via +0x8000 carry) ---------------
__device__ __forceinline__ unsigned pk2(float x0, float x1) {
    const unsigned u0 = __float_as_uint(x0) + 0x8000u;
    const unsigned u1 = __float_as_uint(x1) + 0x8000u;
    return (u0 >> 16) | (u1 & 0xffff0000u);
}
#define LOF(u) __uint_as_float((u) << 16)
#define HIF(u) __uint_as_float((u) & 0xffff0000u)

// a-phase: one packed dword feeds h and m dots for elements E, E+1
#define ADOT2(au, E)                                            \
    { const float aL = LOF(au), aH = HIF(au);                   \
      s0 = fmaf(aL, h[(E)],     s0); r0 = fmaf(aL, m[(E)],     r0); \
      s1 = fmaf(aH, h[(E) + 1], s1); r1 = fmaf(aH, m[(E) + 1], r1); }

// update-phase: packed b/q/k dwords + two fp32 w values for elements E, E+1
#define STEP2(bu, qu, ku, wA, wB, E)                                    \
    { const float bL = LOF(bu), bH = HIF(bu);                           \
      const float qL = LOF(qu), qH = HIF(qu);                           \
      const float kL = LOF(ku), kH = HIF(ku);                           \
      h[(E)]     = fmaf(wA, h[(E)],     fmaf(bL, ah, kL * u));          \
      m[(E)]     = fmaf(wA, m[(E)],     bL * am);                       \
      o0 = fmaf(qL, h[(E)], o0);     z0 = fmaf(qL, m[(E)], z0);         \
      h[(E) + 1] = fmaf(wB, h[(E) + 1], fmaf(bH, ah, kH * u));          \
      m[(E) + 1] = fmaf(wB, m[(E) + 1], bH * am);                       \
      o1 = fmaf(qH, h[(E) + 1], o1); z1 = fmaf(qH, m[(E) + 1], z1); }

// ---------------------------------------------------------------------------
// Phase 1: MERGED G+M scan, ONE 64-thread wave per (bh,p) segment, both
// states (h[64], m[64]) in VGPRs. LDS-broadcast traffic minimized: a,b,q,k
// staged as packed bf16 pairs (8 b128 reads each instead of 16); w = exp(gk)
// and v stay fp32 (w errors compound multiplicatively -> must be exact).
// Single wave => DS ops are in-order => NO barriers anywhere.
// __launch_bounds__(64,1): leave the allocator free (r13's voluntary 128-reg
// cap spilled the 128-float state; r11's forced cap was worse).
// ---------------------------------------------------------------------------
template<int SEG, int CH>
__global__ __launch_bounds__(64, 1) void scan_gm(
    const float* __restrict__ qp, const float* __restrict__ kp,
    const float* __restrict__ vp, const float* __restrict__ ap,
    const float* __restrict__ bp, const float* __restrict__ gkp,
    float* __restrict__ Gbuf, float* __restrict__ Mbuf,
    float* __restrict__ zbuf, float* __restrict__ out)
{
    constexpr int NP = Ss / SEG;
    const int lane = (int)threadIdx.x;           // 0..63
    const int bid  = (int)blockIdx.x;            // bh*NP + p
    const int p    = bid & (NP - 1);
    const int bh   = bid / NP;
    const int b    = bh >> 5, hh = bh & (Hh - 1);
    const size_t segbase = (size_t)bid * (SEG * Dd);

    __shared__ float    lw_[CH * 64];            // exp(gk), fp32
    __shared__ float    lv [CH * 64];            // v, fp32
    __shared__ unsigned laP[CH * 32];            // a, bf16 pairs
    __shared__ unsigned lbP[CH * 32];            // b
    __shared__ unsigned lqP[CH * 32];            // q
    __shared__ unsigned lkP[CH * 32];            // k

    float h[64], m[64];
#pragma unroll
    for (int j = 0; j < 64; ++j) {
        h[j] = 0.f;
        m[j] = (j == lane) ? 1.f : 0.f;
    }

    for (int c0 = 0; c0 < SEG; c0 += CH) {
        // ---- stage CH steps (no barrier: same wave writes and reads)
        {
            const size_t gb = segbase + (size_t)c0 * 64;
#pragma unroll
            for (int i = lane; i < CH * 16; i += 64) {
                const float4 av = ((const float4*)(ap  + gb))[i];
                const float4 bv = ((const float4*)(bp  + gb))[i];
                const float4 qv = ((const float4*)(qp  + gb))[i];
                const float4 kv = ((const float4*)(kp  + gb))[i];
                const float4 gv = ((const float4*)(gkp + gb))[i];
                const float4 vv = ((const float4*)(vp  + gb))[i];
                float4 e;
                e.x = __expf(gv.x); e.y = __expf(gv.y);
                e.z = __expf(gv.z); e.w = __expf(gv.w);
                ((float4*)lw_)[i] = e;
                ((float4*)lv )[i] = vv;
                uint2 pa; pa.x = pk2(av.x, av.y); pa.y = pk2(av.z, av.w);
                uint2 pb; pb.x = pk2(bv.x, bv.y); pb.y = pk2(bv.z, bv.w);
                uint2 pq; pq.x = pk2(qv.x, qv.y); pq.y = pk2(qv.z, qv.w);
                uint2 pk_; pk_.x = pk2(kv.x, kv.y); pk_.y = pk2(kv.z, kv.w);
                ((uint2*)laP)[i] = pa;
                ((uint2*)lbP)[i] = pb;
                ((uint2*)lqP)[i] = pq;
                ((uint2*)lkP)[i] = pk_;
            }
        }

#pragma unroll
        for (int tl = 0; tl < CH; ++tl) {
            const int t = c0 + tl;
            // ---- ah = a^T h, am = a^T m (8 packed b128 reads feed both)
            const uint4* aP = (const uint4*)(laP + tl * 32);
            float s0 = 0.f, s1 = 0.f, r0 = 0.f, r1 = 0.f;
#pragma unroll
            for (int jj = 0; jj < 8; ++jj) {
                const uint4 ua = aP[jj];
                const int e = 8 * jj;
                ADOT2(ua.x, e + 0);
                ADOT2(ua.y, e + 2);
                ADOT2(ua.z, e + 4);
                ADOT2(ua.w, e + 6);
            }
            const float ah = s0 + s1;
            const float am = r0 + r1;

            // ---- both state updates + both q-dots
            const uint4*  bP = (const uint4*)(lbP + tl * 32);
            const uint4*  qP = (const uint4*)(lqP + tl * 32);
            const uint4*  kP = (const uint4*)(lkP + tl * 32);
            const float4* wr = (const float4*)(lw_ + tl * 64);
            const float u = lv[tl * 64 + lane];
            float o0 = 0.f, o1 = 0.f, z0 = 0.f, z1 = 0.f;
#pragma unroll
            for (int jj = 0; jj < 8; ++jj) {
                const uint4 ub = bP[jj];
                const uint4 uq = qP[jj];
                const uint4 uk = kP[jj];
                const float4 w0 = wr[2 * jj], w1 = wr[2 * jj + 1];
                const int e = 8 * jj;
                STEP2(ub.x, uq.x, uk.x, w0.x, w0.y, e + 0);
                STEP2(ub.y, uq.y, uk.y, w0.z, w0.w, e + 2);
                STEP2(ub.z, uq.z, uk.z, w1.x, w1.y, e + 4);
                STEP2(ub.w, uq.w, uk.w, w1.z, w1.w, e + 6);
            }
            const int s = p * SEG + t;
            out[(((size_t)b * Ss + s) * Hh + hh) * Dd + lane] = o0 + o1;
            zbuf[segbase + (size_t)t * 64 + lane] = z0 + z1;
        }
    }

    float* gd = Gbuf + (size_t)bid * 4096;
    float* md = Mbuf + (size_t)bid * 4096;
#pragma unroll
    for (int j = 0; j < 64; ++j) {
        gd[j * 64 + lane] = h[j];
        md[j * 64 + lane] = m[j];
    }
}

// ---------------------------------------------------------------------------
// Phase 2 (proven r8-r13, unchanged): SW_p = M_p * SW_{p-1} + G_p.
// XCD-aware: bh = bid & 63 -> 4 col-blocks of a bh land on the same XCD.
// ---------------------------------------------------------------------------
template<int NP>
__global__ __launch_bounds__(256) void combine(
    const float* __restrict__ Mbuf, float* __restrict__ Gbuf)
{
    const int bh  = (int)blockIdx.x & (NBH - 1);
    const int cb  = (int)blockIdx.x >> 6;
    const int c0  = cb * 16;
    const int tid = (int)threadIdx.x;
    const int cl  = tid & 15;
    const int c   = c0 + cl;
    const int rg  = tid >> 4;            // 0..15
    const int r0  = rg * 4;
    const int xorv = (rg & 1) << 2;

    __shared__ float4 Ml[2][1024];
    __shared__ __align__(16) float swT[16][68];

    {
        const float* G0 = Gbuf + (size_t)bh * NP * 4096;
        for (int i = tid; i < 1024; i += 256)
            swT[i & 15][i >> 4] = G0[(i >> 4) * 64 + c0 + (i & 15)];
    }

    float4 mreg[4];
    if (NP > 1) {
        const float4* Mp = (const float4*)(Mbuf + ((size_t)bh * NP + 1) * 4096);
#pragma unroll
        for (int j = 0; j < 4; ++j) mreg[j] = Mp[j * 256 + tid];
    }
    __syncthreads();
#pragma unroll
    for (int j = 0; j < 4; ++j) {
        const int f = j * 256 + tid;
        Ml[0][f ^ ((f >> 4) & 4)] = mreg[j];
    }
    if (NP > 2) {
        const float4* Mp = (const float4*)(Mbuf + ((size_t)bh * NP + 2) * 4096);
#pragma unroll
        for (int j = 0; j < 4; ++j) mreg[j] = Mp[j * 256 + tid];
    }
    __syncthreads();

    for (int p = 1; p < NP; ++p) {
        const int par = (p - 1) & 1;
        float* Gp = Gbuf + ((size_t)bh * NP + p) * 4096;

        float gacc[4];
#pragma unroll
        for (int r = 0; r < 4; ++r) gacc[r] = Gp[(r0 + r) * 64 + c];

        float accA[4] = {0.f, 0.f, 0.f, 0.f};
        float accB[4] = {0.f, 0.f, 0.f, 0.f};
        const float4* swr = (const float4*)&swT[cl][0];
#pragma unroll
        for (int m4 = 0; m4 < 16; ++m4) {
            const float4 s = swr[m4];
            const int ms = m4 ^ xorv;
#pragma unroll
            for (int r = 0; r < 4; ++r) {
                const float4 m = Ml[par][(r0 + r) * 16 + ms];
                accA[r] = fmaf(m.x, s.x, fmaf(m.y, s.y, accA[r]));
                accB[r] = fmaf(m.z, s.z, fmaf(m.w, s.w, accB[r]));
            }
        }
        __syncthreads();

#pragma unroll
        for (int r = 0; r < 4; ++r) {
            const float val = accA[r] + accB[r] + gacc[r];
            swT[cl][r0 + r] = val;
            Gp[(r0 + r) * 64 + c] = val;
        }
        if (p + 1 < NP) {
#pragma unroll
            for (int j = 0; j < 4; ++j) {
                const int f = j * 256 + tid;
                Ml[par ^ 1][f ^ ((f >> 4) & 4)] = mreg[j];
            }
        }
        if (p + 2 < NP) {
            const float4* Mp = (const float4*)(Mbuf + ((size_t)bh * NP + p + 2) * 4096);
#pragma unroll
            for (int j = 0; j < 4; ++j) mreg[j] = Mp[j * 256 + tid];
        }
        __syncthreads();
    }
}

// ---------------------------------------------------------------------------
// Phase 3 (proven r8-r13, unchanged): out[t] += z_t^T SW_{p-1}.
// ---------------------------------------------------------------------------
template<int SEG>
__global__ __launch_bounds__(256) void seg_correct(
    const float* __restrict__ Gbuf, const float* __restrict__ zbuf,
    float* __restrict__ out)
{
    constexpr int NP = Ss / SEG;
    const int bid = (int)blockIdx.x;              // bh*(NP-1) + (p-1)
    const int bh  = bid / (NP - 1);
    const int p   = bid % (NP - 1) + 1;
    const int tid = (int)threadIdx.x;
    const int lane = tid & 63;
    const int w    = tid >> 6;
    const int b = bh >> 5, hh = bh & (Hh - 1);

    __shared__ float SWs[4096];
    __shared__ float zs[SEG * 64];

    const float* sw = Gbuf + ((size_t)bh * NP + p - 1) * 4096;
    const float* zp = zbuf + ((size_t)(bh * NP + p)) * (SEG * 64);
    for (int i = tid; i < 4096; i += 256)
        SWs[i] = sw[i];
    for (int i = tid; i < SEG * 64; i += 256)
        zs[i] = zp[i];
    __syncthreads();

    for (int t = w; t < SEG; t += 4) {
        float a0 = 0.f, a1 = 0.f, a2 = 0.f, a3 = 0.f;
#pragma unroll
        for (int k = 0; k < 64; k += 4) {
            a0 = fmaf(zs[t * 64 + k + 0], SWs[(k + 0) * 64 + lane], a0);
            a1 = fmaf(zs[t * 64 + k + 1], SWs[(k + 1) * 64 + lane], a1);
            a2 = fmaf(zs[t * 64 + k + 2], SWs[(k + 2) * 64 + lane], a2);
            a3 = fmaf(zs[t * 64 + k + 3], SWs[(k + 3) * 64 + lane], a3);
        }
        const int s = p * SEG + t;
        const size_t o = (((size_t)b * Ss + s) * Hh + hh) * Dd + lane;
        out[o] += (a0 + a1) + (a2 + a3);
    }
}

// ---------------------------------------------------------------------------
// Epilogue (unchanged): in-place GroupNorm + correction + gate on d_out.
// ---------------------------------------------------------------------------
__global__ __launch_bounds__(256) void epilogue(
    const float* __restrict__ qp, const float* __restrict__ kp,
    const float* __restrict__ vp, const float* __restrict__ rk,
    const float* __restrict__ gp, const float* __restrict__ sc,
    const float* __restrict__ bi, float* __restrict__ out)
{
    const int lane = (int)(threadIdx.x & 63u);
    const int gid  = (int)blockIdx.x * 4 + (int)(threadIdx.x >> 6);
    const int hh   = gid & (Hh - 1);
    const int bs   = gid >> 5;
    const int b    = bs >> 10;
    const int s    = bs & (Ss - 1);

    const size_t ioff = ((size_t)(b * Hh + hh) * Ss + s) * Dd + lane;
    const float qv = qp[ioff];
    const float kv = kp[ioff];
    const float vv = vp[ioff];
    const float r  = rk[hh * Dd + lane];

    const size_t goff = (size_t)bs * (Hh * Dd) + hh * Dd + lane;
    const float o = out[goff];

    float s1 = o, s2 = o * o, s3 = qv * kv * r;
#pragma unroll
    for (int m = 32; m >= 1; m >>= 1) {
        s1 += __shfl_xor(s1, m, 64);
        s2 += __shfl_xor(s2, m, 64);
        s3 += __shfl_xor(s3, m, 64);
    }
    const float mu  = s1 * (1.f / 64.f);
    const float var = fmaf(-mu, mu, s2 * (1.f / 64.f));
    const float on  = (o - mu) * rsqrtf(var + 1e-5f);

    out[goff] = (fmaf(on, sc[hh * Dd + lane], bi[hh * Dd + lane]) + s3 * vv) * gp[goff];
}

// ---------------------------------------------------------------------------
extern "C" void kernel_launch(void* const* d_in, const int* in_sizes, int n_in,
                              void* d_out, int out_size, void* d_ws, size_t ws_size,
                              hipStream_t stream)
{
    const float* q   = (const float*)d_in[0];
    const float* k   = (const float*)d_in[1];
    const float* v   = (const float*)d_in[2];
    const float* a   = (const float*)d_in[3];
    const float* b   = (const float*)d_in[4];
    const float* gk  = (const float*)d_in[5];
    const float* r_k = (const float*)d_in[6];
    const float* g   = (const float*)d_in[7];
    const float* gns = (const float*)d_in[8];
    const float* gnb = (const float*)d_in[9];
    float* out = (float*)d_out;
    float* ws  = (float*)d_ws;

    const size_t zfl   = (size_t)NBH * Ss * 64;          // z floats (16.78 MB)
    const size_t gm32  = (size_t)NBH * 32 * 4096;        // G or M floats @NP=32
    const size_t gm16  = (size_t)NBH * 16 * 4096;        // G or M floats @NP=16
    const size_t need32 = (2 * gm32 + zfl) * sizeof(float);   // 83.9 MB
    (void)need32;

    if (ws_size >= need32) {
        // NP=32: 2048 single-wave blocks -> 8 waves/CU.
        float* G = ws;
        float* M = ws + gm32;
        float* Z = ws + 2 * gm32;
        scan_gm<32, 8><<<dim3(NBH * 32), dim3(64), 0, stream>>>(
            q, k, v, a, b, gk, G, M, Z, out);
        combine<32><<<dim3(NBH * 4), dim3(256), 0, stream>>>(M, G);
        seg_correct<32><<<dim3(NBH * 31), dim3(256), 0, stream>>>(G, Z, out);
    } else {
        // NP=16 fallback (50.3 MB).
        float* G = ws;
        float* M = ws + gm16;
        float* Z = ws + 2 * gm16;
        scan_gm<64, 16><<<dim3(NBH * 16), dim3(64), 0, stream>>>(
            q, k, v, a, b, gk, G, M, Z, out);
        combine<16><<<dim3(NBH * 4), dim3(256), 0, stream>>>(M, G);
        seg_correct<64><<<dim3(NBH * 15), dim3(256), 0, stream>>>(G, Z, out);
    }

    epilogue<<<dim3(Bb * Ss * Hh / 4), dim3(256), 0, stream>>>(
        q, k, v, r_k, g, gns, gnb, out);
}